// Round 2
// baseline (2735.417 us; speedup 1.0000x reference)
//
#include <hip/hip_runtime.h>

#define TM 16

typedef unsigned short bfraw;

static __device__ __forceinline__ float bf2f(bfraw u) {
    unsigned int x = ((unsigned int)u) << 16;
    union { unsigned int i; float f; } c; c.i = x; return c.f;
}
static __device__ __forceinline__ bfraw f2bf(float f) {
    union { float f; unsigned int i; } c; c.f = f;
    unsigned int r = c.i + 0x7fffu + ((c.i >> 16) & 1u);
    return (bfraw)(r >> 16);
}

// ---------------- inp = f_bonds @ W_i (bf16) ; msg = relu(inp) (bf16) --------
__global__ __launch_bounds__(320) void k_in(const float* __restrict__ fb,
                                            const float* __restrict__ Wi,
                                            bfraw* __restrict__ inp,
                                            bfraw* __restrict__ msg) {
    __shared__ float As[TM][152];  // 147 padded to 152 (16B-aligned rows)
    const int row0 = blockIdx.x * TM;
    const int tid = threadIdx.x;
    for (int idx = tid; idx < TM * 152; idx += 320) {
        int r = idx / 152, k = idx - r * 152;
        As[r][k] = (k < 147) ? fb[(row0 + r) * 147 + k] : 0.f;
    }
    __syncthreads();
    const int col = tid;
    if (col < 300) {
        float acc[TM];
#pragma unroll
        for (int r = 0; r < TM; ++r) acc[r] = 0.f;
        for (int k0 = 0; k0 < 148; k0 += 4) {
            float w0 = Wi[(k0 + 0) * 300 + col];
            float w1 = Wi[(k0 + 1) * 300 + col];
            float w2 = Wi[(k0 + 2) * 300 + col];
            float w3 = (k0 + 3 < 147) ? Wi[(k0 + 3) * 300 + col] : 0.f;
#pragma unroll
            for (int r = 0; r < TM; ++r) {
                const float4 a = *(const float4*)&As[r][k0];
                acc[r] = fmaf(a.x, w0, acc[r]);
                acc[r] = fmaf(a.y, w1, acc[r]);
                acc[r] = fmaf(a.z, w2, acc[r]);
                acc[r] = fmaf(a.w, w3, acc[r]);
            }
        }
#pragma unroll
        for (int r = 0; r < TM; ++r) {
            const int o = (row0 + r) * 300 + col;
            inp[o] = f2bf(acc[r]);
            msg[o] = f2bf(fmaxf(acc[r], 0.f));
        }
    }
}

// ---------------- a_msg[a] = sum_nb msg[a2b[a][nb]]  (bf16 in/out) -----------
__global__ __launch_bounds__(256) void k_gather(const bfraw* __restrict__ msg,
                                                const int* __restrict__ a2b,
                                                bfraw* __restrict__ amsg) {
    const int gid = blockIdx.x * 256 + threadIdx.x;
    if (gid >= 100000 * 75) return;
    const int a = gid / 75;
    const int c4 = (gid - a * 75) * 4;
    const int* nb = &a2b[a * 6];
    float s0 = 0.f, s1 = 0.f, s2 = 0.f, s3 = 0.f;
#pragma unroll
    for (int j = 0; j < 6; ++j) {
        const ushort4 v = *(const ushort4*)&msg[nb[j] * 300 + c4];
        s0 += bf2f(v.x); s1 += bf2f(v.y); s2 += bf2f(v.z); s3 += bf2f(v.w);
    }
    ushort4 o;
    o.x = f2bf(s0); o.y = f2bf(s1); o.z = f2bf(s2); o.w = f2bf(s3);
    *(ushort4*)&amsg[a * 300 + c4] = o;
}

// ------- msg_out = relu(inp + (amsg[b2a] - msg[b2revb]) @ W_h)  (bf16) -------
__global__ __launch_bounds__(320) void k_bond(const bfraw* __restrict__ amsg,
                                              const bfraw* __restrict__ msg,
                                              const bfraw* __restrict__ inp,
                                              const int* __restrict__ b2a,
                                              const int* __restrict__ b2revb,
                                              const float* __restrict__ Wh,
                                              bfraw* __restrict__ out) {
    __shared__ float As[TM][304];
    const int row0 = blockIdx.x * TM;
    const int tid = threadIdx.x;
    for (int idx = tid; idx < TM * 75; idx += 320) {
        int r = idx / 75, g = idx - r * 75;
        int b = row0 + r;
        const ushort4 va = *(const ushort4*)&amsg[b2a[b] * 300 + g * 4];
        const ushort4 vm = *(const ushort4*)&msg[b2revb[b] * 300 + g * 4];
        As[r][g * 4 + 0] = bf2f(va.x) - bf2f(vm.x);
        As[r][g * 4 + 1] = bf2f(va.y) - bf2f(vm.y);
        As[r][g * 4 + 2] = bf2f(va.z) - bf2f(vm.z);
        As[r][g * 4 + 3] = bf2f(va.w) - bf2f(vm.w);
    }
    __syncthreads();
    const int col = tid;
    if (col < 300) {
        float acc[TM];
#pragma unroll
        for (int r = 0; r < TM; ++r) acc[r] = 0.f;
        for (int k0 = 0; k0 < 300; k0 += 4) {
            float w0 = Wh[(k0 + 0) * 300 + col];
            float w1 = Wh[(k0 + 1) * 300 + col];
            float w2 = Wh[(k0 + 2) * 300 + col];
            float w3 = Wh[(k0 + 3) * 300 + col];
#pragma unroll
            for (int r = 0; r < TM; ++r) {
                const float4 a = *(const float4*)&As[r][k0];
                acc[r] = fmaf(a.x, w0, acc[r]);
                acc[r] = fmaf(a.y, w1, acc[r]);
                acc[r] = fmaf(a.z, w2, acc[r]);
                acc[r] = fmaf(a.w, w3, acc[r]);
            }
        }
#pragma unroll
        for (int r = 0; r < TM; ++r) {
            const int o = (row0 + r) * 300 + col;
            out[o] = f2bf(fmaxf(bf2f(inp[o]) + acc[r], 0.f));
        }
    }
}

// ------- hid = relu(concat(f_atoms, amsg) @ W_o + b_o)  (fp32 out) -----------
__global__ __launch_bounds__(320) void k_out(const float* __restrict__ fa,
                                             const bfraw* __restrict__ amsg,
                                             const float* __restrict__ Wo,
                                             const float* __restrict__ bo,
                                             float* __restrict__ hid) {
    __shared__ float As[TM][436];  // 433 padded to 436 (16B-aligned rows)
    const int row0 = blockIdx.x * TM;
    const int tid = threadIdx.x;
    for (int idx = tid; idx < TM * 436; idx += 320) {
        int r = idx / 436, k = idx - r * 436;
        int a = row0 + r;
        float v = 0.f;
        if (k < 133) v = fa[a * 133 + k];
        else if (k < 433) v = bf2f(amsg[a * 300 + (k - 133)]);
        As[r][k] = v;
    }
    __syncthreads();
    const int col = tid;
    if (col < 300) {
        float acc[TM];
#pragma unroll
        for (int r = 0; r < TM; ++r) acc[r] = 0.f;
        for (int k0 = 0; k0 < 436; k0 += 4) {
            float w0 = Wo[(k0 + 0) * 300 + col];  // k0 <= 432 < 433 always
            float w1 = (k0 + 1 < 433) ? Wo[(k0 + 1) * 300 + col] : 0.f;
            float w2 = (k0 + 2 < 433) ? Wo[(k0 + 2) * 300 + col] : 0.f;
            float w3 = (k0 + 3 < 433) ? Wo[(k0 + 3) * 300 + col] : 0.f;
#pragma unroll
            for (int r = 0; r < TM; ++r) {
                const float4 a = *(const float4*)&As[r][k0];
                acc[r] = fmaf(a.x, w0, acc[r]);
                acc[r] = fmaf(a.y, w1, acc[r]);
                acc[r] = fmaf(a.z, w2, acc[r]);
                acc[r] = fmaf(a.w, w3, acc[r]);
            }
        }
        const float b = bo[col];
#pragma unroll
        for (int r = 0; r < TM; ++r) {
            hid[(row0 + r) * 300 + col] = fmaxf(acc[r] + b, 0.f);
        }
    }
}

// ------- out[m] = mean of hid rows with mol_ids == m (0 if none) -------------
__global__ __launch_bounds__(320) void k_mean(const float* __restrict__ hid,
                                              const int* __restrict__ mol,
                                              float* __restrict__ out) {
    const int m = blockIdx.x;
    const int natoms = 100000;
    int lo = 0, hi = natoms;
    while (lo < hi) { int mid = (lo + hi) >> 1; if (mol[mid] < m) lo = mid + 1; else hi = mid; }
    const int start = lo;
    lo = start; hi = natoms;
    while (lo < hi) { int mid = (lo + hi) >> 1; if (mol[mid] <= m) lo = mid + 1; else hi = mid; }
    const int end = lo;
    const int col = threadIdx.x;
    if (col >= 300) return;
    float s = 0.f;
    for (int a = start; a < end; ++a) s += hid[a * 300 + col];
    const int n = end - start;
    out[m * 300 + col] = (n > 0) ? (s / (float)n) : 0.f;
}

extern "C" void kernel_launch(void* const* d_in, const int* in_sizes, int n_in,
                              void* d_out, int out_size, void* d_ws, size_t ws_size,
                              hipStream_t stream) {
    const float* f_atoms = (const float*)d_in[0];
    const float* f_bonds = (const float*)d_in[1];
    const int* a2b      = (const int*)d_in[2];
    const int* b2a      = (const int*)d_in[3];
    const int* b2revb   = (const int*)d_in[4];
    const int* mol_ids  = (const int*)d_in[5];
    const float* W_i    = (const float*)d_in[6];
    const float* W_h    = (const float*)d_in[7];
    const float* W_o    = (const float*)d_in[8];
    const float* b_o    = (const float*)d_in[9];
    float* out = (float*)d_out;

    // Workspace layout (bf16 intermediates, 420 MB total):
    //   inp  : 200000*300 bf16 = 120 MB   @ 0
    //   msgA : 200000*300 bf16 = 120 MB   @ 120 MB
    //   msgB : 200000*300 bf16 = 120 MB   @ 240 MB
    //   amsg : 100000*300 bf16 =  60 MB   @ 360 MB
    //   hid  : 100000*300 fp32 = 120 MB   @ 240 MB (reuses dead msgB)
    char* wsb = (char*)d_ws;
    bfraw* inp  = (bfraw*)(wsb);
    bfraw* msgA = (bfraw*)(wsb + 120000000ll);
    bfraw* msgB = (bfraw*)(wsb + 240000000ll);
    bfraw* amsg = (bfraw*)(wsb + 360000000ll);

    const int nb_blocks = 200000 / TM;   // 12500
    const int na_blocks = 100000 / TM;   // 6250
    const int gather_blocks = (100000 * 75 + 255) / 256;

    k_in<<<nb_blocks, 320, 0, stream>>>(f_bonds, W_i, inp, msgA);

    bfraw* cur = msgA;
    bfraw* nxt = msgB;
    for (int d = 0; d < 2; ++d) {
        k_gather<<<gather_blocks, 256, 0, stream>>>(cur, a2b, amsg);
        k_bond<<<nb_blocks, 320, 0, stream>>>(amsg, cur, inp, b2a, b2revb, W_h, nxt);
        bfraw* t = cur; cur = nxt; nxt = t;
    }
    k_gather<<<gather_blocks, 256, 0, stream>>>(cur, a2b, amsg);
    // cur == msgA here; msgB (== nxt) is dead -> reuse as fp32 hid
    float* hid = (float*)(wsb + 240000000ll);
    k_out<<<na_blocks, 320, 0, stream>>>(f_atoms, amsg, W_o, b_o, hid);
    k_mean<<<4000, 320, 0, stream>>>(hid, mol_ids, out);
}

// Round 3
// 871.211 us; speedup vs baseline: 3.1398x; 3.1398x over previous
//
#include <hip/hip_runtime.h>

typedef unsigned short bfraw;
typedef __attribute__((ext_vector_type(8))) short short8v;
typedef __attribute__((ext_vector_type(8))) unsigned short ushort8v;
typedef __attribute__((ext_vector_type(4))) float f32x4;

static __device__ __forceinline__ float bf2f(unsigned short u) {
    union { unsigned int i; float f; } c; c.i = ((unsigned int)u) << 16; return c.f;
}
static __device__ __forceinline__ unsigned short f2bf(float f) {
    union { float f; unsigned int i; } c; c.f = f;
    unsigned int r = c.i + 0x7fffu + ((c.i >> 16) & 1u);
    return (unsigned short)(r >> 16);
}
static __device__ __forceinline__ f32x4 mfma16(short8v a, short8v b, f32x4 c) {
    return __builtin_amdgcn_mfma_f32_16x16x32_bf16(a, b, c, 0, 0, 0);
}

// Pack W (fp32 [Krows][300], starting at row_off) into MFMA B-fragment order:
// Bp[((ks*20+ct)*64+l)*8+j] = W[ks*32+(l>>4)*8+j][ct*16+(l&15)]  (0 outside)
__global__ __launch_bounds__(64) void k_pack(const float* __restrict__ W, int Krows, int row_off,
                                             bfraw* __restrict__ out) {
    const int b = blockIdx.x;           // b = ks*20 + ct
    const int ks = b / 20, ct = b - ks * 20;
    const int l = threadIdx.x;
    const int n = ct * 16 + (l & 15);
    const int kb = ks * 32 + (l >> 4) * 8;
    short8v pk;
#pragma unroll
    for (int j = 0; j < 8; ++j) {
        int k = kb + j;
        float v = (k < Krows && n < 300) ? W[(row_off + k) * 300 + n] : 0.f;
        pk[j] = (short)f2bf(v);
    }
    *(short8v*)&out[(b * 64 + l) * 8] = pk;
}

// ---------------- inp = f_bonds @ W_i ; msg = relu(inp)  (bf16, stride 304) --
__global__ __launch_bounds__(256) void k_in(const float* __restrict__ fb,
                                            const bfraw* __restrict__ Wp,
                                            bfraw* __restrict__ inp,
                                            bfraw* __restrict__ msg) {
    __shared__ short A[64 * 24 * 8];   // 64 rows x 24 chunks(16B) : K=160 pad, swizzled
    const int row0 = blockIdx.x * 64;
    const int tid = threadIdx.x;
    for (int idx = tid; idx < 64 * 20; idx += 256) {
        int r = idx / 20, c = idx - r * 20;
        const int kbase = c * 8;
        const float* src = fb + (long long)(row0 + r) * 147 + kbase;
        short8v pk;
#pragma unroll
        for (int j = 0; j < 8; ++j) {
            float v = (kbase + j < 147) ? src[j] : 0.f;
            pk[j] = (short)f2bf(v);
        }
        *(short8v*)&A[(r * 24 + (c ^ (r & 7))) * 8] = pk;
    }
    __syncthreads();
    const int w = tid >> 6, l = tid & 63;
    const int lr = l & 15, lk = l >> 4, sw = l & 7;
    f32x4 acc[4][5];
#pragma unroll
    for (int rt = 0; rt < 4; ++rt)
#pragma unroll
        for (int i = 0; i < 5; ++i) acc[rt][i] = (f32x4){0.f, 0.f, 0.f, 0.f};
    const short8v* Ald = (const short8v*)A;
#pragma unroll
    for (int ks = 0; ks < 5; ++ks) {
        short8v a[4], bfv[5];
#pragma unroll
        for (int rt = 0; rt < 4; ++rt)
            a[rt] = Ald[(rt * 16 + lr) * 24 + ((ks * 4 + lk) ^ sw)];
#pragma unroll
        for (int i = 0; i < 5; ++i)
            bfv[i] = *(const short8v*)&Wp[((ks * 20 + w * 5 + i) * 64 + l) * 8];
#pragma unroll
        for (int rt = 0; rt < 4; ++rt)
#pragma unroll
            for (int i = 0; i < 5; ++i)
                acc[rt][i] = mfma16(a[rt], bfv[i], acc[rt][i]);
    }
#pragma unroll
    for (int rt = 0; rt < 4; ++rt)
#pragma unroll
        for (int i = 0; i < 5; ++i) {
            const int col = (w * 5 + i) * 16 + lr;
            if (col < 304) {
#pragma unroll
                for (int v = 0; v < 4; ++v) {
                    const int row = row0 + rt * 16 + lk * 4 + v;
                    float x = acc[rt][i][v];
                    long long o = (long long)row * 304 + col;
                    inp[o] = f2bf(x);
                    msg[o] = f2bf(fmaxf(x, 0.f));
                }
            }
        }
}

// ---------------- a_msg[a] = sum_nb msg[a2b[a][nb]]  (bf16, stride 304) ------
__global__ __launch_bounds__(256) void k_gather(const bfraw* __restrict__ msg,
                                                const int* __restrict__ a2b,
                                                bfraw* __restrict__ amsg) {
    int gid = blockIdx.x * 256 + threadIdx.x;
    if (gid >= 100000 * 38) return;
    int a = gid / 38, c = gid - a * 38;
    const int* nb = a2b + a * 6;
    float s[8];
#pragma unroll
    for (int e = 0; e < 8; ++e) s[e] = 0.f;
#pragma unroll
    for (int j = 0; j < 6; ++j) {
        const ushort8v v = *(const ushort8v*)&msg[(long long)nb[j] * 304 + c * 8];
#pragma unroll
        for (int e = 0; e < 8; ++e) s[e] += bf2f(v[e]);
    }
    short8v o;
#pragma unroll
    for (int e = 0; e < 8; ++e) o[e] = (short)f2bf(s[e]);
    *(short8v*)&amsg[(long long)a * 304 + c * 8] = o;
}

// ------- out = relu(inp + (amsg[b2a] - msg[b2revb]) @ W_h)  (bf16) -----------
__global__ __launch_bounds__(256) void k_bond(const bfraw* __restrict__ amsg,
                                              const bfraw* __restrict__ msg,
                                              const bfraw* __restrict__ inp,
                                              const int* __restrict__ b2a,
                                              const int* __restrict__ b2revb,
                                              const bfraw* __restrict__ Wp,
                                              bfraw* __restrict__ out) {
    __shared__ short A[64 * 40 * 8];   // 64 rows x 40 chunks : K=320 pad, swizzled
    const int row0 = blockIdx.x * 64;
    const int tid = threadIdx.x;
    for (int idx = tid; idx < 64 * 40; idx += 256) {
        int r = idx / 40, c = idx - r * 40;
        short8v pk;
        if (c < 38) {
            int b = row0 + r;
            const ushort8v va = *(const ushort8v*)&amsg[(long long)b2a[b] * 304 + c * 8];
            const ushort8v vm = *(const ushort8v*)&msg[(long long)b2revb[b] * 304 + c * 8];
#pragma unroll
            for (int j = 0; j < 8; ++j)
                pk[j] = (short)f2bf(bf2f(va[j]) - bf2f(vm[j]));
        } else {
#pragma unroll
            for (int j = 0; j < 8; ++j) pk[j] = 0;
        }
        *(short8v*)&A[(r * 40 + (c ^ (r & 7))) * 8] = pk;
    }
    __syncthreads();
    const int w = tid >> 6, l = tid & 63;
    const int lr = l & 15, lk = l >> 4, sw = l & 7;
    f32x4 acc[4][5];
#pragma unroll
    for (int rt = 0; rt < 4; ++rt)
#pragma unroll
        for (int i = 0; i < 5; ++i) acc[rt][i] = (f32x4){0.f, 0.f, 0.f, 0.f};
    const short8v* Ald = (const short8v*)A;
#pragma unroll
    for (int ks = 0; ks < 10; ++ks) {
        short8v a[4], bfv[5];
#pragma unroll
        for (int rt = 0; rt < 4; ++rt)
            a[rt] = Ald[(rt * 16 + lr) * 40 + ((ks * 4 + lk) ^ sw)];
#pragma unroll
        for (int i = 0; i < 5; ++i)
            bfv[i] = *(const short8v*)&Wp[((ks * 20 + w * 5 + i) * 64 + l) * 8];
#pragma unroll
        for (int rt = 0; rt < 4; ++rt)
#pragma unroll
            for (int i = 0; i < 5; ++i)
                acc[rt][i] = mfma16(a[rt], bfv[i], acc[rt][i]);
    }
#pragma unroll
    for (int rt = 0; rt < 4; ++rt)
#pragma unroll
        for (int i = 0; i < 5; ++i) {
            const int col = (w * 5 + i) * 16 + lr;
            if (col < 304) {
#pragma unroll
                for (int v = 0; v < 4; ++v) {
                    const int row = row0 + rt * 16 + lk * 4 + v;
                    long long o = (long long)row * 304 + col;
                    float x = bf2f(inp[o]) + acc[rt][i][v];
                    out[o] = f2bf(fmaxf(x, 0.f));
                }
            }
        }
}

// ------- hid = relu(f_atoms @ Wo_fa + amsg @ Wo_am + b_o)  (fp32, stride 304)
__global__ __launch_bounds__(256) void k_out(const float* __restrict__ fa,
                                             const bfraw* __restrict__ amsg,
                                             const bfraw* __restrict__ WfP,
                                             const bfraw* __restrict__ WaP,
                                             const float* __restrict__ bo,
                                             float* __restrict__ hid) {
    __shared__ short Af[64 * 24 * 8];
    __shared__ short Am[64 * 40 * 8];
    const int row0 = blockIdx.x * 64;
    const int tid = threadIdx.x;
    for (int idx = tid; idx < 64 * 20; idx += 256) {
        int r = idx / 20, c = idx - r * 20;
        const int row = row0 + r;
        const int kbase = c * 8;
        short8v pk;
        if (row < 100000) {
            const float* src = fa + (long long)row * 133 + kbase;
#pragma unroll
            for (int j = 0; j < 8; ++j) {
                float v = (kbase + j < 133) ? src[j] : 0.f;
                pk[j] = (short)f2bf(v);
            }
        } else {
#pragma unroll
            for (int j = 0; j < 8; ++j) pk[j] = 0;
        }
        *(short8v*)&Af[(r * 24 + (c ^ (r & 7))) * 8] = pk;
    }
    for (int idx = tid; idx < 64 * 40; idx += 256) {
        int r = idx / 40, c = idx - r * 40;
        const int row = row0 + r;
        short8v pk;
        if (c < 38 && row < 100000) {
            const ushort8v v = *(const ushort8v*)&amsg[(long long)row * 304 + c * 8];
#pragma unroll
            for (int j = 0; j < 8; ++j) pk[j] = (short)v[j];
        } else {
#pragma unroll
            for (int j = 0; j < 8; ++j) pk[j] = 0;
        }
        *(short8v*)&Am[(r * 40 + (c ^ (r & 7))) * 8] = pk;
    }
    __syncthreads();
    const int w = tid >> 6, l = tid & 63;
    const int lr = l & 15, lk = l >> 4, sw = l & 7;
    f32x4 acc[4][5];
#pragma unroll
    for (int rt = 0; rt < 4; ++rt)
#pragma unroll
        for (int i = 0; i < 5; ++i) acc[rt][i] = (f32x4){0.f, 0.f, 0.f, 0.f};
    const short8v* Afl = (const short8v*)Af;
    const short8v* Aml = (const short8v*)Am;
#pragma unroll
    for (int ks = 0; ks < 5; ++ks) {
        short8v a[4], bfv[5];
#pragma unroll
        for (int rt = 0; rt < 4; ++rt)
            a[rt] = Afl[(rt * 16 + lr) * 24 + ((ks * 4 + lk) ^ sw)];
#pragma unroll
        for (int i = 0; i < 5; ++i)
            bfv[i] = *(const short8v*)&WfP[((ks * 20 + w * 5 + i) * 64 + l) * 8];
#pragma unroll
        for (int rt = 0; rt < 4; ++rt)
#pragma unroll
            for (int i = 0; i < 5; ++i)
                acc[rt][i] = mfma16(a[rt], bfv[i], acc[rt][i]);
    }
#pragma unroll
    for (int ks = 0; ks < 10; ++ks) {
        short8v a[4], bfv[5];
#pragma unroll
        for (int rt = 0; rt < 4; ++rt)
            a[rt] = Aml[(rt * 16 + lr) * 40 + ((ks * 4 + lk) ^ sw)];
#pragma unroll
        for (int i = 0; i < 5; ++i)
            bfv[i] = *(const short8v*)&WaP[((ks * 20 + w * 5 + i) * 64 + l) * 8];
#pragma unroll
        for (int rt = 0; rt < 4; ++rt)
#pragma unroll
            for (int i = 0; i < 5; ++i)
                acc[rt][i] = mfma16(a[rt], bfv[i], acc[rt][i]);
    }
#pragma unroll
    for (int rt = 0; rt < 4; ++rt)
#pragma unroll
        for (int i = 0; i < 5; ++i) {
            const int col = (w * 5 + i) * 16 + lr;
            const float bias = (col < 300) ? bo[col] : 0.f;
            if (col < 304) {
#pragma unroll
                for (int v = 0; v < 4; ++v) {
                    const int row = row0 + rt * 16 + lk * 4 + v;
                    if (row < 100000)
                        hid[(long long)row * 304 + col] = fmaxf(acc[rt][i][v] + bias, 0.f);
                }
            }
        }
}

// ------- out[m] = mean of hid rows with mol_ids == m (0 if none) -------------
__global__ __launch_bounds__(320) void k_mean(const float* __restrict__ hid,
                                              const int* __restrict__ mol,
                                              float* __restrict__ out) {
    const int m = blockIdx.x;
    const int natoms = 100000;
    int lo = 0, hi = natoms;
    while (lo < hi) { int mid = (lo + hi) >> 1; if (mol[mid] < m) lo = mid + 1; else hi = mid; }
    const int start = lo;
    lo = start; hi = natoms;
    while (lo < hi) { int mid = (lo + hi) >> 1; if (mol[mid] <= m) lo = mid + 1; else hi = mid; }
    const int end = lo;
    const int col = threadIdx.x;
    if (col >= 300) return;
    float s = 0.f;
    for (int a = start; a < end; ++a) s += hid[(long long)a * 304 + col];
    const int n = end - start;
    out[m * 300 + col] = (n > 0) ? (s / (float)n) : 0.f;
}

extern "C" void kernel_launch(void* const* d_in, const int* in_sizes, int n_in,
                              void* d_out, int out_size, void* d_ws, size_t ws_size,
                              hipStream_t stream) {
    const float* f_atoms = (const float*)d_in[0];
    const float* f_bonds = (const float*)d_in[1];
    const int* a2b      = (const int*)d_in[2];
    const int* b2a      = (const int*)d_in[3];
    const int* b2revb   = (const int*)d_in[4];
    const int* mol_ids  = (const int*)d_in[5];
    const float* W_i    = (const float*)d_in[6];
    const float* W_h    = (const float*)d_in[7];
    const float* W_o    = (const float*)d_in[8];
    const float* b_o    = (const float*)d_in[9];
    float* out = (float*)d_out;

    // ws layout (bytes): all bf16 rows at stride 304 (608 B, 16B-aligned)
    //   inp  @ 0            121,600,000
    //   msgA @ 121,600,000  121,600,000
    //   msgB @ 243,200,000  121,600,000  (reused as fp32 hid after bond2)
    //   amsg @ 364,800,000   60,800,000
    //   packed weights @ 425,600,000 (~0.6 MB)
    char* wsb = (char*)d_ws;
    bfraw* inp  = (bfraw*)(wsb);
    bfraw* msgA = (bfraw*)(wsb + 121600000ll);
    bfraw* msgB = (bfraw*)(wsb + 243200000ll);
    bfraw* amsg = (bfraw*)(wsb + 364800000ll);
    bfraw* WiP   = (bfraw*)(wsb + 425600000ll);            // 5*20*64*8*2  = 102400 B
    bfraw* WhP   = (bfraw*)(wsb + 425702400ll);            // 10*20*64*8*2 = 204800 B
    bfraw* WoFaP = (bfraw*)(wsb + 425907200ll);            // 102400 B
    bfraw* WoAmP = (bfraw*)(wsb + 426009600ll);            // 204800 B

    k_pack<<<100, 64, 0, stream>>>(W_i, 147, 0, WiP);
    k_pack<<<200, 64, 0, stream>>>(W_h, 300, 0, WhP);
    k_pack<<<100, 64, 0, stream>>>(W_o, 133, 0, WoFaP);
    k_pack<<<200, 64, 0, stream>>>(W_o, 300, 133, WoAmP);

    const int nb_blocks = 200000 / 64;          // 3125
    const int na_blocks = (100000 + 63) / 64;   // 1563
    const int gather_blocks = (100000 * 38 + 255) / 256;

    k_in<<<nb_blocks, 256, 0, stream>>>(f_bonds, WiP, inp, msgA);

    bfraw* cur = msgA;
    bfraw* nxt = msgB;
    for (int d = 0; d < 2; ++d) {
        k_gather<<<gather_blocks, 256, 0, stream>>>(cur, a2b, amsg);
        k_bond<<<nb_blocks, 256, 0, stream>>>(amsg, cur, inp, b2a, b2revb, WhP, nxt);
        bfraw* t = cur; cur = nxt; nxt = t;
    }
    k_gather<<<gather_blocks, 256, 0, stream>>>(cur, a2b, amsg);

    float* hid = (float*)(wsb + 243200000ll);   // dead msgB region
    k_out<<<na_blocks, 256, 0, stream>>>(f_atoms, amsg, WoFaP, WoAmP, b_o, hid);
    k_mean<<<4000, 320, 0, stream>>>(hid, mol_ids, out);
}

// Round 4
// 802.456 us; speedup vs baseline: 3.4088x; 1.0857x over previous
//
#include <hip/hip_runtime.h>

typedef unsigned short bfraw;
typedef __attribute__((ext_vector_type(8))) short short8v;
typedef __attribute__((ext_vector_type(8))) unsigned short ushort8v;
typedef __attribute__((ext_vector_type(4))) float f32x4;

static __device__ __forceinline__ float bf2f(unsigned short u) {
    union { unsigned int i; float f; } c; c.i = ((unsigned int)u) << 16; return c.f;
}
static __device__ __forceinline__ unsigned short f2bf(float f) {
    union { float f; unsigned int i; } c; c.f = f;
    unsigned int r = c.i + 0x7fffu + ((c.i >> 16) & 1u);
    return (unsigned short)(r >> 16);
}
static __device__ __forceinline__ unsigned short brelu(unsigned short u) {
    return (u & 0x8000u) ? (unsigned short)0 : u;   // bf16 relu via sign bit (exact)
}
static __device__ __forceinline__ f32x4 mfma16(short8v a, short8v b, f32x4 c) {
    return __builtin_amdgcn_mfma_f32_16x16x32_bf16(a, b, c, 0, 0, 0);
}

// Pack W (fp32 [Krows][300], starting at row_off) into MFMA B-fragment order:
// Bp[((ks*20+ct)*64+l)*8+j] = W[ks*32+(l>>4)*8+j][ct*16+(l&15)]  (0 outside)
__global__ __launch_bounds__(64) void k_pack(const float* __restrict__ W, int Krows, int row_off,
                                             bfraw* __restrict__ out) {
    const int b = blockIdx.x;           // b = ks*20 + ct
    const int ks = b / 20, ct = b - ks * 20;
    const int l = threadIdx.x;
    const int n = ct * 16 + (l & 15);
    const int kb = ks * 32 + (l >> 4) * 8;
    short8v pk;
#pragma unroll
    for (int j = 0; j < 8; ++j) {
        int k = kb + j;
        float v = (k < Krows && n < 300) ? W[(row_off + k) * 300 + n] : 0.f;
        pk[j] = (short)f2bf(v);
    }
    *(short8v*)&out[(b * 64 + l) * 8] = pk;
}

// ---------------- inp = f_bonds @ W_i ; msg = relu(inp)  (bf16, stride 304) --
__global__ __launch_bounds__(256) void k_in(const float* __restrict__ fb,
                                            const bfraw* __restrict__ Wp,
                                            bfraw* __restrict__ inp,
                                            bfraw* __restrict__ msg) {
    __shared__ short A[64 * 320];   // 40960 B; staging stride 24 chunks, epilogue [64][320]
    const int row0 = blockIdx.x * 64;
    const int tid = threadIdx.x;
    for (int idx = tid; idx < 64 * 20; idx += 256) {
        int r = idx / 20, c = idx - r * 20;
        const int kbase = c * 8;
        const float* src = fb + (long long)(row0 + r) * 147 + kbase;
        short8v pk;
#pragma unroll
        for (int j = 0; j < 8; ++j) {
            float v = (kbase + j < 147) ? src[j] : 0.f;
            pk[j] = (short)f2bf(v);
        }
        *(short8v*)&A[(r * 24 + (c ^ (r & 7))) * 8] = pk;
    }
    __syncthreads();
    const int w = tid >> 6, l = tid & 63;
    const int lr = l & 15, lk = l >> 4, sw = l & 7;
    f32x4 acc[4][5];
#pragma unroll
    for (int rt = 0; rt < 4; ++rt)
#pragma unroll
        for (int i = 0; i < 5; ++i) acc[rt][i] = (f32x4){0.f, 0.f, 0.f, 0.f};
    const short8v* Ald = (const short8v*)A;
#pragma unroll
    for (int ks = 0; ks < 5; ++ks) {
        short8v a[4], bfv[5];
#pragma unroll
        for (int rt = 0; rt < 4; ++rt)
            a[rt] = Ald[(rt * 16 + lr) * 24 + ((ks * 4 + lk) ^ sw)];
#pragma unroll
        for (int i = 0; i < 5; ++i)
            bfv[i] = *(const short8v*)&Wp[((ks * 20 + w * 5 + i) * 64 + l) * 8];
#pragma unroll
        for (int rt = 0; rt < 4; ++rt)
#pragma unroll
            for (int i = 0; i < 5; ++i)
                acc[rt][i] = mfma16(a[rt], bfv[i], acc[rt][i]);
    }
    __syncthreads();   // done reading staged A; reuse as transpose buffer
#pragma unroll
    for (int rt = 0; rt < 4; ++rt)
#pragma unroll
        for (int i = 0; i < 5; ++i) {
            const int col = (w * 5 + i) * 16 + lr;
#pragma unroll
            for (int v = 0; v < 4; ++v)
                A[(rt * 16 + lk * 4 + v) * 320 + col] = (short)f2bf(acc[rt][i][v]);
        }
    __syncthreads();
    for (int idx = tid; idx < 64 * 38; idx += 256) {
        int r = idx / 38, c = idx - r * 38;
        short8v t = *(const short8v*)&A[r * 320 + c * 8];
        long long o = (long long)(row0 + r) * 304 + c * 8;
        *(short8v*)&inp[o] = t;
        short8v m;
#pragma unroll
        for (int j = 0; j < 8; ++j) m[j] = (short)brelu((unsigned short)t[j]);
        *(short8v*)&msg[o] = m;
    }
}

// ---------------- a_msg[a] = sum_nb msg[a2b[a][nb]]  (bf16, stride 304) ------
__global__ __launch_bounds__(256) void k_gather(const bfraw* __restrict__ msg,
                                                const int* __restrict__ a2b,
                                                bfraw* __restrict__ amsg) {
    int gid = blockIdx.x * 256 + threadIdx.x;
    if (gid >= 100000 * 19) return;
    int a = gid / 19, c = gid - a * 19;      // handles chunks c and c+19
    const int* nb = a2b + a * 6;
    float s0[8], s1[8];
#pragma unroll
    for (int e = 0; e < 8; ++e) { s0[e] = 0.f; s1[e] = 0.f; }
#pragma unroll
    for (int j = 0; j < 6; ++j) {
        const long long base = (long long)nb[j] * 304;
        const ushort8v v0 = *(const ushort8v*)&msg[base + c * 8];
        const ushort8v v1 = *(const ushort8v*)&msg[base + (c + 19) * 8];
#pragma unroll
        for (int e = 0; e < 8; ++e) { s0[e] += bf2f(v0[e]); s1[e] += bf2f(v1[e]); }
    }
    short8v o0, o1;
#pragma unroll
    for (int e = 0; e < 8; ++e) { o0[e] = (short)f2bf(s0[e]); o1[e] = (short)f2bf(s1[e]); }
    *(short8v*)&amsg[(long long)a * 304 + c * 8] = o0;
    *(short8v*)&amsg[(long long)a * 304 + (c + 19) * 8] = o1;
}

// ------- out = relu(inp + (amsg[b2a] - msg[b2revb]) @ W_h)  (bf16) -----------
__global__ __launch_bounds__(256) void k_bond(const bfraw* __restrict__ amsg,
                                              const bfraw* __restrict__ msg,
                                              const bfraw* __restrict__ inp,
                                              const int* __restrict__ b2a,
                                              const int* __restrict__ b2revb,
                                              const bfraw* __restrict__ Wp,
                                              bfraw* __restrict__ out) {
    __shared__ short A[64 * 320];   // 40960 B; staging stride 40 chunks, epilogue [64][320]
    const int row0 = blockIdx.x * 64;
    const int tid = threadIdx.x;
    for (int idx = tid; idx < 64 * 40; idx += 256) {
        int r = idx / 40, c = idx - r * 40;
        short8v pk;
        if (c < 38) {
            int b = row0 + r;
            const ushort8v va = *(const ushort8v*)&amsg[(long long)b2a[b] * 304 + c * 8];
            const ushort8v vm = *(const ushort8v*)&msg[(long long)b2revb[b] * 304 + c * 8];
#pragma unroll
            for (int j = 0; j < 8; ++j)
                pk[j] = (short)f2bf(bf2f(va[j]) - bf2f(vm[j]));
        } else {
#pragma unroll
            for (int j = 0; j < 8; ++j) pk[j] = 0;
        }
        *(short8v*)&A[(r * 40 + (c ^ (r & 7))) * 8] = pk;
    }
    __syncthreads();
    const int w = tid >> 6, l = tid & 63;
    const int lr = l & 15, lk = l >> 4, sw = l & 7;
    f32x4 acc[4][5];
#pragma unroll
    for (int rt = 0; rt < 4; ++rt)
#pragma unroll
        for (int i = 0; i < 5; ++i) acc[rt][i] = (f32x4){0.f, 0.f, 0.f, 0.f};
    const short8v* Ald = (const short8v*)A;
#pragma unroll
    for (int ks = 0; ks < 10; ++ks) {
        short8v a[4], bfv[5];
#pragma unroll
        for (int rt = 0; rt < 4; ++rt)
            a[rt] = Ald[(rt * 16 + lr) * 40 + ((ks * 4 + lk) ^ sw)];
#pragma unroll
        for (int i = 0; i < 5; ++i)
            bfv[i] = *(const short8v*)&Wp[((ks * 20 + w * 5 + i) * 64 + l) * 8];
#pragma unroll
        for (int rt = 0; rt < 4; ++rt)
#pragma unroll
            for (int i = 0; i < 5; ++i)
                acc[rt][i] = mfma16(a[rt], bfv[i], acc[rt][i]);
    }
    __syncthreads();
#pragma unroll
    for (int rt = 0; rt < 4; ++rt)
#pragma unroll
        for (int i = 0; i < 5; ++i) {
            const int col = (w * 5 + i) * 16 + lr;
#pragma unroll
            for (int v = 0; v < 4; ++v)
                A[(rt * 16 + lk * 4 + v) * 320 + col] = (short)f2bf(acc[rt][i][v]);
        }
    __syncthreads();
    for (int idx = tid; idx < 64 * 38; idx += 256) {
        int r = idx / 38, c = idx - r * 38;
        short8v t = *(const short8v*)&A[r * 320 + c * 8];
        long long o = (long long)(row0 + r) * 304 + c * 8;
        const ushort8v ip = *(const ushort8v*)&inp[o];
        short8v m;
#pragma unroll
        for (int j = 0; j < 8; ++j) {
            float x = bf2f(ip[j]) + bf2f((unsigned short)t[j]);
            m[j] = (short)f2bf(fmaxf(x, 0.f));
        }
        *(short8v*)&out[o] = m;
    }
}

// ------- hid = relu(f_atoms @ Wo_fa + amsg @ Wo_am + b_o)  (bf16, stride 304)
__global__ __launch_bounds__(256) void k_out(const float* __restrict__ fa,
                                             const bfraw* __restrict__ amsg,
                                             const bfraw* __restrict__ WfP,
                                             const bfraw* __restrict__ WaP,
                                             const float* __restrict__ bo,
                                             bfraw* __restrict__ hid) {
    __shared__ short Af[64 * 192];   // stride 24 chunks
    __shared__ short Am[64 * 320];   // staging stride 40 chunks; epilogue [64][320]
    const int row0 = blockIdx.x * 64;
    const int tid = threadIdx.x;
    for (int idx = tid; idx < 64 * 20; idx += 256) {
        int r = idx / 20, c = idx - r * 20;
        const int row = row0 + r;
        const int kbase = c * 8;
        short8v pk;
        if (row < 100000) {
            const float* src = fa + (long long)row * 133 + kbase;
#pragma unroll
            for (int j = 0; j < 8; ++j) {
                float v = (kbase + j < 133) ? src[j] : 0.f;
                pk[j] = (short)f2bf(v);
            }
        } else {
#pragma unroll
            for (int j = 0; j < 8; ++j) pk[j] = 0;
        }
        *(short8v*)&Af[(r * 24 + (c ^ (r & 7))) * 8] = pk;
    }
    for (int idx = tid; idx < 64 * 40; idx += 256) {
        int r = idx / 40, c = idx - r * 40;
        const int row = row0 + r;
        short8v pk;
        if (c < 38 && row < 100000) {
            const ushort8v v = *(const ushort8v*)&amsg[(long long)row * 304 + c * 8];
#pragma unroll
            for (int j = 0; j < 8; ++j) pk[j] = (short)v[j];
        } else {
#pragma unroll
            for (int j = 0; j < 8; ++j) pk[j] = 0;
        }
        *(short8v*)&Am[(r * 40 + (c ^ (r & 7))) * 8] = pk;
    }
    __syncthreads();
    const int w = tid >> 6, l = tid & 63;
    const int lr = l & 15, lk = l >> 4, sw = l & 7;
    f32x4 acc[4][5];
#pragma unroll
    for (int rt = 0; rt < 4; ++rt)
#pragma unroll
        for (int i = 0; i < 5; ++i) acc[rt][i] = (f32x4){0.f, 0.f, 0.f, 0.f};
    const short8v* Afl = (const short8v*)Af;
    const short8v* Aml = (const short8v*)Am;
#pragma unroll
    for (int ks = 0; ks < 5; ++ks) {
        short8v a[4], bfv[5];
#pragma unroll
        for (int rt = 0; rt < 4; ++rt)
            a[rt] = Afl[(rt * 16 + lr) * 24 + ((ks * 4 + lk) ^ sw)];
#pragma unroll
        for (int i = 0; i < 5; ++i)
            bfv[i] = *(const short8v*)&WfP[((ks * 20 + w * 5 + i) * 64 + l) * 8];
#pragma unroll
        for (int rt = 0; rt < 4; ++rt)
#pragma unroll
            for (int i = 0; i < 5; ++i)
                acc[rt][i] = mfma16(a[rt], bfv[i], acc[rt][i]);
    }
#pragma unroll
    for (int ks = 0; ks < 10; ++ks) {
        short8v a[4], bfv[5];
#pragma unroll
        for (int rt = 0; rt < 4; ++rt)
            a[rt] = Aml[(rt * 16 + lr) * 40 + ((ks * 4 + lk) ^ sw)];
#pragma unroll
        for (int i = 0; i < 5; ++i)
            bfv[i] = *(const short8v*)&WaP[((ks * 20 + w * 5 + i) * 64 + l) * 8];
#pragma unroll
        for (int rt = 0; rt < 4; ++rt)
#pragma unroll
            for (int i = 0; i < 5; ++i)
                acc[rt][i] = mfma16(a[rt], bfv[i], acc[rt][i]);
    }
    __syncthreads();
#pragma unroll
    for (int rt = 0; rt < 4; ++rt)
#pragma unroll
        for (int i = 0; i < 5; ++i) {
            const int col = (w * 5 + i) * 16 + lr;
            const float bias = (col < 300) ? bo[col] : 0.f;
#pragma unroll
            for (int v = 0; v < 4; ++v)
                Am[(rt * 16 + lk * 4 + v) * 320 + col] =
                    (short)f2bf(fmaxf(acc[rt][i][v] + bias, 0.f));
        }
    __syncthreads();
    for (int idx = tid; idx < 64 * 38; idx += 256) {
        int r = idx / 38, c = idx - r * 38;
        const int row = row0 + r;
        if (row < 100000) {
            short8v t = *(const short8v*)&Am[r * 320 + c * 8];
            *(short8v*)&hid[(long long)row * 304 + c * 8] = t;
        }
    }
}

// ------- out[m] = mean of hid rows with mol_ids == m (0 if none) -------------
__global__ __launch_bounds__(320) void k_mean(const bfraw* __restrict__ hid,
                                              const int* __restrict__ mol,
                                              float* __restrict__ out) {
    const int m = blockIdx.x;
    const int natoms = 100000;
    int lo = 0, hi = natoms;
    while (lo < hi) { int mid = (lo + hi) >> 1; if (mol[mid] < m) lo = mid + 1; else hi = mid; }
    const int start = lo;
    lo = start; hi = natoms;
    while (lo < hi) { int mid = (lo + hi) >> 1; if (mol[mid] <= m) lo = mid + 1; else hi = mid; }
    const int end = lo;
    const int col = threadIdx.x;
    if (col >= 300) return;
    float s = 0.f;
    for (int a = start; a < end; ++a) s += bf2f(hid[(long long)a * 304 + col]);
    const int n = end - start;
    out[m * 300 + col] = (n > 0) ? (s / (float)n) : 0.f;
}

extern "C" void kernel_launch(void* const* d_in, const int* in_sizes, int n_in,
                              void* d_out, int out_size, void* d_ws, size_t ws_size,
                              hipStream_t stream) {
    const float* f_atoms = (const float*)d_in[0];
    const float* f_bonds = (const float*)d_in[1];
    const int* a2b      = (const int*)d_in[2];
    const int* b2a      = (const int*)d_in[3];
    const int* b2revb   = (const int*)d_in[4];
    const int* mol_ids  = (const int*)d_in[5];
    const float* W_i    = (const float*)d_in[6];
    const float* W_h    = (const float*)d_in[7];
    const float* W_o    = (const float*)d_in[8];
    const float* b_o    = (const float*)d_in[9];
    float* out = (float*)d_out;

    // ws layout (bytes): bf16 rows at stride 304 (608 B)
    //   inp  @ 0            121,600,000
    //   msgA @ 121,600,000  121,600,000
    //   msgB @ 243,200,000  121,600,000  (reused as bf16 hid after bond2)
    //   amsg @ 364,800,000   60,800,000
    //   packed weights @ 425,600,000 (~0.6 MB)
    char* wsb = (char*)d_ws;
    bfraw* inp  = (bfraw*)(wsb);
    bfraw* msgA = (bfraw*)(wsb + 121600000ll);
    bfraw* msgB = (bfraw*)(wsb + 243200000ll);
    bfraw* amsg = (bfraw*)(wsb + 364800000ll);
    bfraw* WiP   = (bfraw*)(wsb + 425600000ll);
    bfraw* WhP   = (bfraw*)(wsb + 425702400ll);
    bfraw* WoFaP = (bfraw*)(wsb + 425907200ll);
    bfraw* WoAmP = (bfraw*)(wsb + 426009600ll);

    k_pack<<<100, 64, 0, stream>>>(W_i, 147, 0, WiP);
    k_pack<<<200, 64, 0, stream>>>(W_h, 300, 0, WhP);
    k_pack<<<100, 64, 0, stream>>>(W_o, 133, 0, WoFaP);
    k_pack<<<200, 64, 0, stream>>>(W_o, 300, 133, WoAmP);

    const int nb_blocks = 200000 / 64;          // 3125
    const int na_blocks = (100000 + 63) / 64;   // 1563
    const int gather_blocks = (100000 * 19 + 255) / 256;

    k_in<<<nb_blocks, 256, 0, stream>>>(f_bonds, WiP, inp, msgA);

    bfraw* cur = msgA;
    bfraw* nxt = msgB;
    for (int d = 0; d < 2; ++d) {
        k_gather<<<gather_blocks, 256, 0, stream>>>(cur, a2b, amsg);
        k_bond<<<nb_blocks, 256, 0, stream>>>(amsg, cur, inp, b2a, b2revb, WhP, nxt);
        bfraw* t = cur; cur = nxt; nxt = t;
    }
    k_gather<<<gather_blocks, 256, 0, stream>>>(cur, a2b, amsg);

    bfraw* hid = (bfraw*)(wsb + 243200000ll);   // dead msgB region
    k_out<<<na_blocks, 256, 0, stream>>>(f_atoms, amsg, WoFaP, WoAmP, b_o, hid);
    k_mean<<<4000, 320, 0, stream>>>(hid, mol_ids, out);
}